// Round 5
// baseline (64.657 us; speedup 1.0000x reference)
//
#include <hip/hip_runtime.h>
#include <cstdint>

#define EMBED      2048
#define NEXP       16
#define NWAVES     8                    // d-split waves per block
#define TOKB       64                   // tokens per block (one per lane)
#define WINF       64                   // floats per window per token
#define NWIN       (EMBED / WINF)       // 32 windows
#define NBUF       4                    // pipeline depth (counted-vmcnt)
#define NTOK_TOTAL (8 * 4096)
#define WOFF       (NTOK_TOTAL * 2)     // float offset of indices region in d_out
#define PAD        17                   // epilogue LDS row pad

__device__ __forceinline__ void g2l16(const float* g, float* l) {
    __builtin_amdgcn_global_load_lds(
        (const __attribute__((address_space(1))) void*)(uintptr_t)g,
        (__attribute__((address_space(3))) void*)(uintptr_t)l,
        16, 0, 0);
}
__device__ __forceinline__ void g2l4(const float* g, float* l) {
    __builtin_amdgcn_global_load_lds(
        (const __attribute__((address_space(1))) void*)(uintptr_t)g,
        (__attribute__((address_space(3))) void*)(uintptr_t)l,
        4, 0, 0);
}

// R4 structure (LDS-staged x + W, broadcast W reads, zero VMEM/SMEM in the
// compute path) upgraded from 2-buffer __syncthreads (vmcnt(0) drain of the
// JUST-issued prefetch every window — the m97-style barrier stall) to a
// 4-buffer pipeline with counted vmcnt + raw s_barrier:
//   steady state: 3 windows (12 loads/thread) in flight, barrier waits
//   vmcnt(8) -> the needed window's loads were issued ~2 windows (~1200 cy)
//   earlier, covering HBM latency. lgkmcnt(0) before each barrier protects
//   buffer reuse (stage(win+4) overwrites buf[win&3]).
// 80 KB LDS -> 2 blocks/CU = 16 waves/CU.
extern "C" __global__ __launch_bounds__(NWAVES * 64, 4)
void router_kernel(const float* __restrict__ x,
                   const float* __restrict__ gw,
                   float* __restrict__ out)
{
    __shared__ float lds_x[NBUF][TOKB * WINF];   // 4 x 16 KB
    __shared__ float lds_w[NBUF][NEXP * WINF];   // 4 x  4 KB

    const int tid  = threadIdx.x;
    const int lane = tid & 63;
    const int W    = __builtin_amdgcn_readfirstlane(tid >> 6);
    const int t0   = blockIdx.x * TOKB;

    float acc[NEXP];
#pragma unroll
    for (int e = 0; e < NEXP; ++e) acc[e] = 0.0f;

    // stage one x window (16 KB = 1024 granules, 2/thread). LDS filled
    // LINEARLY at granule G; global source granule inverse-swizzled with the
    // involution  s(g) = (g&8) | ((g^row)&7)   (8-cycle-optimal b128 reads)
    auto stage_x = [&](int win, int buf) {
#pragma unroll
        for (int it = 0; it < 2; ++it) {
            const int G    = it * 512 + tid;   // granule in tile (16B units)
            const int row  = G >> 4;           // local token
            const int pos  = G & 15;           // slot within row (16 granules)
            const int gsrc = (pos & 8) | ((pos ^ row) & 7);
            const float* src = x + (size_t)(t0 + row) * EMBED + win * WINF + gsrc * 4;
            g2l16(src, &lds_x[buf][G * 4]);
        }
    };

    // stage one W window (4 KB = 1024 dwords, 2 dword-loads/thread so the
    // per-window vmcnt contribution is uniform = 4 across all waves)
    auto stage_w = [&](int win, int buf) {
#pragma unroll
        for (int it = 0; it < 2; ++it) {
            const int q = it * 512 + tid;      // dword index in window
            const int e = q >> 6;              // 0..15
            const int f = q & 63;              // float within row
            g2l4(gw + e * EMBED + win * WINF + f, &lds_w[buf][q]);
        }
    };

    // compute one window from buf: 2 swizzled x-reads + 32 broadcast W-reads
    // + 128 FMA4 per lane
    auto compute = [&](int win, int buf) {
        const float* bx = lds_x[buf];
        const float* bw = lds_w[buf];
#pragma unroll
        for (int j = 0; j < 2; ++j) {
            const int g   = W * 2 + j;                     // my granule 0..15
            const int pos = (g & 8) | ((g ^ lane) & 7);    // swizzled x slot
            const float4 x4 = *(const float4*)&bx[lane * WINF + pos * 4];
#pragma unroll
            for (int e = 0; e < NEXP; ++e) {
                const float4 w4 = *(const float4*)&bw[e * WINF + g * 4]; // broadcast
                acc[e] = fmaf(x4.x, w4.x, acc[e]);
                acc[e] = fmaf(x4.y, w4.y, acc[e]);
                acc[e] = fmaf(x4.z, w4.z, acc[e]);
                acc[e] = fmaf(x4.w, w4.w, acc[e]);
            }
        }
    };

    // ---- prologue: fill 3 of 4 buffers (12 loads/thread in flight) ----
    stage_x(0, 0); stage_w(0, 0);
    stage_x(1, 1); stage_w(1, 1);
    stage_x(2, 2); stage_w(2, 2);
    asm volatile("s_waitcnt vmcnt(8)" ::: "memory");   // window 0 complete
    __builtin_amdgcn_s_barrier();
    asm volatile("" ::: "memory");

    // ---- main loop: windows 0 .. NWIN-4 ----
    for (int win = 0; win < NWIN - 3; ++win) {
        stage_x(win + 3, (win + 3) & 3);     // issue-early (4 loads)
        stage_w(win + 3, (win + 3) & 3);
        compute(win, win & 3);
        // reads of buf[win&3] done (lgkm=0) before next iter's stage
        // overwrites it; win+1's stage (issued 2 windows ago) complete
        // (vmcnt<=8 leaves only win+2/win+3 in flight).
        asm volatile("s_waitcnt vmcnt(8) lgkmcnt(0)" ::: "memory");
        __builtin_amdgcn_s_barrier();
        asm volatile("" ::: "memory");
    }
    // ---- epilogue windows: drain 8 -> 4 -> 0 ----
    compute(NWIN - 3, (NWIN - 3) & 3);
    asm volatile("s_waitcnt vmcnt(4) lgkmcnt(0)" ::: "memory");
    __builtin_amdgcn_s_barrier();
    asm volatile("" ::: "memory");
    compute(NWIN - 2, (NWIN - 2) & 3);
    asm volatile("s_waitcnt vmcnt(0) lgkmcnt(0)" ::: "memory");
    __builtin_amdgcn_s_barrier();
    asm volatile("" ::: "memory");
    compute(NWIN - 1, (NWIN - 1) & 3);
    // no barrier: part overlays buf0..2; all waves are past window NWIN-2
    // (last barrier), and window NWIN-1 touches only buf3.

    // cross-wave reduction (overlay scratch on lds_x buffers 0-2)
    float (*part)[TOKB][PAD] = (float (*)[TOKB][PAD])lds_x;
#pragma unroll
    for (int e = 0; e < NEXP; ++e) part[W][lane][e] = acc[e];
    __syncthreads();

    if (tid < TOKB) {               // wave 0 only: uniform branch
        float tot[NEXP];
#pragma unroll
        for (int e = 0; e < NEXP; ++e) tot[e] = 0.0f;
#pragma unroll
        for (int w = 0; w < NWAVES; ++w) {
#pragma unroll
            for (int e = 0; e < NEXP; ++e) tot[e] += part[w][tid][e];
        }

        // top-2 with lowest-index tie-break (strict >)
        float m1 = tot[0]; int i1 = 0;
#pragma unroll
        for (int e = 1; e < NEXP; ++e) {
            if (tot[e] > m1) { m1 = tot[e]; i1 = e; }
        }
        float m2 = -INFINITY; int i2 = 0;
#pragma unroll
        for (int e = 0; e < NEXP; ++e) {
            const bool sel = (e != i1) && (tot[e] > m2);
            if (sel) { m2 = tot[e]; i2 = e; }
        }

        // normalized top-2 weights = softmax over the two logits
        const float ed = __expf(m2 - m1);   // <= 1
        const float w1 = 1.0f / (1.0f + ed);
        const float w2 = 1.0f - w1;

        const int t = t0 + tid;
        out[t * 2 + 0] = w1;
        out[t * 2 + 1] = w2;
        out[WOFF + t * 2 + 0] = (float)i1;
        out[WOFF + t * 2 + 1] = (float)i2;
    }
}

extern "C" void kernel_launch(void* const* d_in, const int* in_sizes, int n_in,
                              void* d_out, int out_size, void* d_ws, size_t ws_size,
                              hipStream_t stream) {
    const float* x  = (const float*)d_in[0];   // [8,4096,2048] f32
    const float* gw = (const float*)d_in[1];   // [16,2048] f32
    float* out = (float*)d_out;                // weights[65536] ++ indices-as-f32[65536]

    const int nblocks = NTOK_TOTAL / TOKB;     // 512 blocks x 512 threads
    router_kernel<<<dim3(nblocks), dim3(NWAVES * 64), 0, stream>>>(x, gw, out);
}

// Round 6
// 63.795 us; speedup vs baseline: 1.0135x; 1.0135x over previous
//
#include <hip/hip_runtime.h>
#include <cstdint>

#define EMBED      2048
#define NEXP       16
#define NWAVES     8                    // d-split waves per block
#define TOKB       64                   // tokens per block (one per lane)
#define WINF       128                  // floats per window per token
#define NWIN       (EMBED / WINF)       // 16 windows
#define NTOK_TOTAL (8 * 4096)
#define WOFF       (NTOK_TOTAL * 2)     // float offset of indices region in d_out
#define PAD        17                   // epilogue LDS row pad

__device__ __forceinline__ void g2l16(const float* g, float* l) {
    __builtin_amdgcn_global_load_lds(
        (const __attribute__((address_space(1))) void*)(uintptr_t)g,
        (__attribute__((address_space(3))) void*)(uintptr_t)l,
        16, 0, 0);
}

// One-time 128 KB transpose: wT[d][e] = gw[e][d]. Makes the 16 experts'
// weights for consecutive d CONTIGUOUS -> wide s_load_dwordx16 in the router.
extern "C" __global__ __launch_bounds__(256)
void transpose_w(const float* __restrict__ gw, float* __restrict__ wT) {
    const int i = blockIdx.x * 256 + threadIdx.x;   // 0..32767
    const int d = i >> 4, e = i & 15;
    wT[i] = gw[e * EMBED + d];
}

// R4's proven x-staging skeleton (WINF=128, 2-buffer, syncthreads, swizzled
// gload_lds) with the W path moved OFF the vector datapath:
//   R4 was LDS-crossbar-bound: 16384 broadcast ds_read_b128 per CU for W,
//   each moving 1024 B through the crossbar for 16 B of unique data
//   (16384 x ~9 cy = ~61 us ~= R4's measured 59.8 us).
//   Now W flows through the SCALAR pipe: wave-uniform reads of transposed
//   Wt in 32-float contiguous chunks -> s_load_dwordx16 pairs -> SGPRs ->
//   v_fmac_f32 v,s,v (1 SGPR operand, legal). Zero W bytes through LDS/VMEM.
//   x reads are HOISTED to the window top so in-loop lgkm tracks only SMEM
//   (R1's fatal ds/SMEM drain coupling removed).
extern "C" __global__ __launch_bounds__(NWAVES * 64, 4)
void router_kernel(const float* __restrict__ x,
                   const float* __restrict__ wT,
                   float* __restrict__ out)
{
    __shared__ float lds_x[2][TOKB * WINF];   // 2 x 32 KB

    const int tid  = threadIdx.x;
    const int lane = tid & 63;
    const int W    = __builtin_amdgcn_readfirstlane(tid >> 6);
    const int t0   = blockIdx.x * TOKB;

    float acc[NEXP];
#pragma unroll
    for (int e = 0; e < NEXP; ++e) acc[e] = 0.0f;

    // stage one x window (32 KB = 2048 granules, 4/thread). LDS filled
    // LINEARLY at granule G; global source inverse-swizzled (R1/R4-proven):
    auto stage_x = [&](int win, int buf) {
#pragma unroll
        for (int it = 0; it < 4; ++it) {
            const int G   = it * 512 + tid;   // granule in tile (16B units)
            const int row = G >> 5;           // local token
            const int pos = G & 31;           // slot within row (32 granules)
            const int g   = (pos & ~7) | ((pos ^ row) & 7);
            const float* src = x + (size_t)(t0 + row) * EMBED + win * WINF + g * 4;
            g2l16(src, &lds_x[buf][G * 4]);
        }
    };

    stage_x(0, 0);
    __syncthreads();

    int cur = 0;
    for (int win = 0; win < NWIN; ++win) {
        if (win + 1 < NWIN) stage_x(win + 1, cur ^ 1);

        const float* bx = lds_x[cur];

        // hoist ALL x reads for this window (4 swizzled ds_read_b128)
        float4 xv[4];
#pragma unroll
        for (int j = 0; j < 4; ++j) {
            const int g   = W * 4 + j;                     // my granule 0..31
            const int pos = (g & ~7) | ((g ^ lane) & 7);   // swizzled x slot
            xv[j] = *(const float4*)&bx[lane * WINF + pos * 4];
        }

        // W via scalar pipe: per granule j, two 32-float chunks
        // (2 d-rows x 16 experts, contiguous in wT) -> s_load_dwordx16 x2
#pragma unroll
        for (int j = 0; j < 4; ++j) {
            const int g = W * 4 + j;
#pragma unroll
            for (int h = 0; h < 2; ++h) {
                const float* wq = wT + (size_t)(win * WINF + g * 4 + h * 2) * NEXP;
                float wt[2 * NEXP];                      // uniform -> SGPRs
#pragma unroll
                for (int i = 0; i < 2 * NEXP; ++i) wt[i] = wq[i];
                const float c0 = (h == 0) ? xv[j].x : xv[j].z;
                const float c1 = (h == 0) ? xv[j].y : xv[j].w;
#pragma unroll
                for (int e = 0; e < NEXP; ++e) acc[e] = fmaf(c0, wt[e], acc[e]);
#pragma unroll
                for (int e = 0; e < NEXP; ++e) acc[e] = fmaf(c1, wt[NEXP + e], acc[e]);
            }
        }
        __syncthreads();
        cur ^= 1;
    }

    // cross-wave reduction (overlay scratch on lds_x; stride-17 rows)
    float (*part)[TOKB][PAD] = (float (*)[TOKB][PAD])lds_x;
#pragma unroll
    for (int e = 0; e < NEXP; ++e) part[W][lane][e] = acc[e];
    __syncthreads();

    if (tid < TOKB) {               // wave 0 only: uniform branch
        float tot[NEXP];
#pragma unroll
        for (int e = 0; e < NEXP; ++e) tot[e] = 0.0f;
#pragma unroll
        for (int w = 0; w < NWAVES; ++w) {
#pragma unroll
            for (int e = 0; e < NEXP; ++e) tot[e] += part[w][tid][e];
        }

        // top-2 with lowest-index tie-break (strict >)
        float m1 = tot[0]; int i1 = 0;
#pragma unroll
        for (int e = 1; e < NEXP; ++e) {
            if (tot[e] > m1) { m1 = tot[e]; i1 = e; }
        }
        float m2 = -INFINITY; int i2 = 0;
#pragma unroll
        for (int e = 0; e < NEXP; ++e) {
            const bool sel = (e != i1) && (tot[e] > m2);
            if (sel) { m2 = tot[e]; i2 = e; }
        }

        // normalized top-2 weights = softmax over the two logits
        const float ed = __expf(m2 - m1);   // <= 1
        const float w1 = 1.0f / (1.0f + ed);
        const float w2 = 1.0f - w1;

        const int t = t0 + tid;
        out[t * 2 + 0] = w1;
        out[t * 2 + 1] = w2;
        out[WOFF + t * 2 + 0] = (float)i1;
        out[WOFF + t * 2 + 1] = (float)i2;
    }
}

extern "C" void kernel_launch(void* const* d_in, const int* in_sizes, int n_in,
                              void* d_out, int out_size, void* d_ws, size_t ws_size,
                              hipStream_t stream) {
    const float* x  = (const float*)d_in[0];   // [8,4096,2048] f32
    const float* gw = (const float*)d_in[1];   // [16,2048] f32
    float* out = (float*)d_out;                // weights[65536] ++ indices-as-f32[65536]
    float* wT  = (float*)d_ws;                 // 128 KB transposed weights

    transpose_w<<<dim3((NEXP * EMBED) / 256), dim3(256), 0, stream>>>(gw, wT);

    const int nblocks = NTOK_TOTAL / TOKB;     // 512 blocks x 512 threads
    router_kernel<<<dim3(nblocks), dim3(NWAVES * 64), 0, stream>>>(x, wT, out);
}